// Round 9
// baseline (1182.066 us; speedup 1.0000x reference)
//
#include <hip/hip_runtime.h>
#include <hip/hip_bf16.h>

#define B_ 2
#define S_ 2048
#define D_ 512
#define H_ 8
#define L_ 6
#define F_ 2048
#define HD_ 64
#define M_ 4096
#define OFF_ 4999
#define NREL_ 9999

typedef short s8v __attribute__((ext_vector_type(8)));
typedef float f4v __attribute__((ext_vector_type(4)));

enum { MODE_BF16 = 0, MODE_RES = 1, MODE_GELU = 2 };

__device__ __forceinline__ short f2bf(float f) {
  unsigned u = __float_as_uint(f);
  unsigned r = (u + 0x7fffu + ((u >> 16) & 1u)) >> 16;
  return (short)r;
}

__device__ __forceinline__ void gload16(const void* g, const void* l) {
  __builtin_amdgcn_global_load_lds((const __attribute__((address_space(1))) unsigned int*)g,
                                   (__attribute__((address_space(3))) unsigned int*)l,
                                   16, 0, 0);
}

// ---------------- weight transpose: src fp32 (K,N) -> dst bf16 (N,K) -------
__global__ void transpose_kernel(const float* __restrict__ src, short* __restrict__ dst,
                                 int K, int N, long srcBS, long dstBS, int rowOff)
{
  __shared__ float t[32][33];
  int tx = threadIdx.x, ty = threadIdx.y;  // block (32,8)
  int n0 = blockIdx.x * 32, k0 = blockIdx.y * 32, l = blockIdx.z;
  const float* s = src + (size_t)l * srcBS;
  short* d = dst + (size_t)l * dstBS;
  for (int j = 0; j < 4; ++j)
    t[ty + j*8][tx] = s[(size_t)(k0 + ty + j*8) * N + n0 + tx];
  __syncthreads();
  for (int j = 0; j < 4; ++j)
    d[(size_t)(rowOff + n0 + ty + j*8) * K + k0 + tx] = f2bf(t[tx][ty + j*8]);
}

__global__ void packb_kernel(const float* __restrict__ bq, const float* __restrict__ bk,
                             const float* __restrict__ bv, float* __restrict__ bqkv)
{
  int i = blockIdx.x * 256 + threadIdx.x;
  if (i >= L_ * 1536) return;
  int l = i / 1536, j = i % 1536;
  float v = (j < 512) ? bq[l*512 + j] : (j < 1024) ? bk[l*512 + j - 512] : bv[l*512 + j - 1024];
  bqkv[i] = v;
}

// ---------------- bias table transpose: tab (L,NREL,H) -> tabT (L,H,NREL) --
__global__ void tabt_kernel(const float* __restrict__ tab, float* __restrict__ tabT)
{
  int i = blockIdx.x * 256 + threadIdx.x;
  if (i >= L_ * H_ * NREL_) return;
  int l = i / (H_ * NREL_), rem = i % (H_ * NREL_);
  int h = rem / NREL_, idx = rem % NREL_;
  tabT[i] = tab[((size_t)l * NREL_ + idx) * H_ + h];
}

// ---------------- spk_emb @ Wspk + bspk: grid (B_, 8), k-split + LDS reduce -
__global__ __launch_bounds__(256) void spk_kernel(const float* __restrict__ spk,
                                                  const float* __restrict__ Wspk,
                                                  const float* __restrict__ bspk,
                                                  float* __restrict__ sproj)
{
  __shared__ float red[4][64];
  int b = blockIdx.x, nb = blockIdx.y;
  int dl = threadIdx.x & 63, kc = threadIdx.x >> 6;
  int d = nb * 64 + dl;
  const float* sprow = spk + b * D_;
  float a0 = 0.f, a1 = 0.f;
  int kbeg = kc * 128;
  for (int k = kbeg; k < kbeg + 128; k += 2) {
    a0 += sprow[k]     * Wspk[(size_t)k * D_ + d];
    a1 += sprow[k + 1] * Wspk[(size_t)(k + 1) * D_ + d];
  }
  red[kc][dl] = a0 + a1;
  __syncthreads();
  if (kc == 0)
    sproj[b*D_ + d] = red[0][dl] + red[1][dl] + red[2][dl] + red[3][dl] + bspk[d];
}

// ---------------- prologue: x + PE + cond encodings -> X fp32 --------------
__global__ __launch_bounds__(256) void prologue_kernel(
    const float* __restrict__ x, const float* __restrict__ f0, const float* __restrict__ sp,
    const float* __restrict__ ap, const float* __restrict__ Wf0, const float* __restrict__ bf0,
    const float* __restrict__ Wsp, const float* __restrict__ bsp,
    const float* __restrict__ Wap, const float* __restrict__ bap,
    const float* __restrict__ sproj, float* __restrict__ X)
{
  int row = blockIdx.x, tid = threadIdx.x;
  int b = row >> 11, s = row & 2047;
  float vf0 = f0[row], vsp = sp[row], vap = ap[row];
  for (int j = 0; j < 2; ++j) {
    int d = tid + j * 256;
    int i = d >> 1;
    float div = expf((float)(2*i) * -0.01798894603f);  // -ln(10000)/512
    float arg = (float)s * div;
    float pe = (d & 1) ? cosf(arg) : sinf(arg);
    float v = x[(size_t)row*D_ + d] + pe
            + vf0*Wf0[d] + bf0[d] + vsp*Wsp[d] + bsp[d] + vap*Wap[d] + bap[d]
            + sproj[b*D_ + d];
    X[(size_t)row*D_ + d] = v;
  }
}

// ---------------- layernorm: X fp32 row -> bf16 (or fp32 final) ------------
__global__ __launch_bounds__(256) void ln_kernel(
    const float* __restrict__ X, const float* __restrict__ g, const float* __restrict__ bta,
    short* __restrict__ outB, float* __restrict__ outF, int f32out)
{
  __shared__ float red[8];
  int row = blockIdx.x, tid = threadIdx.x;
  const float* xr = X + (size_t)row * D_;
  float v0 = xr[tid], v1 = xr[tid + 256];
  float s = v0 + v1, q = v0*v0 + v1*v1;
  for (int off = 1; off < 64; off <<= 1) { s += __shfl_xor(s, off); q += __shfl_xor(q, off); }
  int w = tid >> 6;
  if ((tid & 63) == 0) { red[w*2] = s; red[w*2 + 1] = q; }
  __syncthreads();
  s = red[0] + red[2] + red[4] + red[6];
  q = red[1] + red[3] + red[5] + red[7];
  float mean = s * (1.0f / D_);
  float var = q * (1.0f / D_) - mean * mean;
  float rstd = rsqrtf(var + 1e-5f);
  float o0 = (v0 - mean) * rstd * g[tid] + bta[tid];
  float o1 = (v1 - mean) * rstd * g[tid + 256] + bta[tid + 256];
  if (f32out) {
    outF[(size_t)row*D_ + tid] = o0; outF[(size_t)row*D_ + tid + 256] = o1;
  } else {
    outB[(size_t)row*D_ + tid] = f2bf(o0); outB[(size_t)row*D_ + tid + 256] = f2bf(o1);
  }
}

// ---------------- bf16 MFMA GEMM (round-6 proven DMA K-loop) ---------------
// NOTE (round-7 lesson): register-path prefetch of 6 int4/thread spilled to
// scratch (VGPR=40 reported, 134 MB phantom writes) -> DMA staging only.
template<int MODE>
__device__ __forceinline__ void gemm_body(
    const short* __restrict__ A, const short* __restrict__ Wt,
    const float* __restrict__ bias, int K, int N,
    float* outF, short* outB)
{
  __shared__ short sA[2][4096];  // [panel][128 rows][32 k]
  __shared__ short sB[2][2048];  // [panel][64 rows][32 k]
  const int tid = threadIdx.x;
  const int w = tid >> 6, lane = tid & 63;
  const int col = lane & 15, quad = lane >> 4;
  const int n0 = blockIdx.x * 64, m0 = blockIdx.y * 128;
  const int z = blockIdx.z;
  const int Ksub = K / gridDim.z;
  const int kbase = z * Ksub;
  const int nkt = Ksub >> 6;

  const int rowT = tid >> 2, kcA = tid & 3;
  const size_t kc8 = kcA * 8;

  f4v acc[2][4] = {};
  for (int kt = 0; kt < nkt; ++kt) {
    const int k0 = kbase + kt * 64;
    __syncthreads();
    for (int p = 0; p < 2; ++p) {
      gload16(A + (size_t)(m0 + rowT) * K + k0 + p*32 + kc8,       &sA[p][(w*16) * 32]);
      gload16(A + (size_t)(m0 + 64 + rowT) * K + k0 + p*32 + kc8,  &sA[p][(64 + w*16) * 32]);
      gload16(Wt + (size_t)(n0 + rowT) * K + k0 + p*32 + kc8,      &sB[p][(w*16) * 32]);
    }
    __syncthreads();
    for (int p = 0; p < 2; ++p) {
      s8v af[2], bfr[4];
      for (int mt = 0; mt < 2; ++mt)
        af[mt] = *(const s8v*)&sA[p][(w*32 + mt*16 + col) * 32 + quad * 8];
      for (int nt = 0; nt < 4; ++nt)
        bfr[nt] = *(const s8v*)&sB[p][(nt*16 + col) * 32 + quad * 8];
      for (int mt = 0; mt < 2; ++mt)
        for (int nt = 0; nt < 4; ++nt)
          acc[mt][nt] = __builtin_amdgcn_mfma_f32_16x16x32_bf16(af[mt], bfr[nt], acc[mt][nt], 0, 0, 0);
    }
  }

  float bz[4];
  for (int nt = 0; nt < 4; ++nt)
    bz[nt] = (z == 0) ? bias[n0 + nt*16 + col] : 0.0f;
  for (int mt = 0; mt < 2; ++mt) {
    int mbase = m0 + w*32 + mt*16 + quad*4;
    for (int nt = 0; nt < 4; ++nt) {
      int n = n0 + nt*16 + col;
      for (int r = 0; r < 4; ++r) {
        float v = acc[mt][nt][r] + bz[nt];
        size_t idx = (size_t)(mbase + r) * N + n;
        if (MODE == MODE_RES) {
          atomicAdd(outF + idx, v);
        } else if (MODE == MODE_GELU) {
          outB[idx] = f2bf(0.5f * v * (1.0f + erff(v * 0.70710678118f)));
        } else {
          outB[idx] = f2bf(v);
        }
      }
    }
  }
}

__global__ __launch_bounds__(256) void gemm_qkv_kernel(
    const short* __restrict__ A, const short* __restrict__ Wt,
    const float* __restrict__ bias, float* outF, short* outB)
{ gemm_body<MODE_BF16>(A, Wt, bias, 512, 1536, outF, outB); }

__global__ __launch_bounds__(256) void gemm_o_kernel(
    const short* __restrict__ A, const short* __restrict__ Wt,
    const float* __restrict__ bias, float* outF, short* outB)
{ gemm_body<MODE_RES>(A, Wt, bias, 512, 512, outF, outB); }

__global__ __launch_bounds__(256) void gemm_ffn1_kernel(
    const short* __restrict__ A, const short* __restrict__ Wt,
    const float* __restrict__ bias, float* outF, short* outB)
{ gemm_body<MODE_GELU>(A, Wt, bias, 512, 2048, outF, outB); }

__global__ __launch_bounds__(256) void gemm_ffn2_kernel(
    const short* __restrict__ A, const short* __restrict__ Wt,
    const float* __restrict__ bias, float* outF, short* outB)
{ gemm_body<MODE_RES>(A, Wt, bias, 2048, 512, outF, outB); }

// ---------------- V transpose: QKV V-part (b,s,h,hd) -> Vt (b,h,hd,s) ------
__global__ __launch_bounds__(256) void vtrans_kernel(const short* __restrict__ QKV,
                                                     short* __restrict__ Vt)
{
  __shared__ short t[64 * 72];
  int tid = threadIdx.x;
  int s0 = blockIdx.x * 64, bh = blockIdx.y;
  int b = bh >> 3, h = bh & 7;
  for (int it = 0; it < 2; ++it) {
    int c = it * 256 + tid;
    int sR = c >> 3, hc = c & 7;
    s8v v = *(const s8v*)(QKV + (size_t)(b*S_ + s0 + sR) * 1536 + 1024 + h*64 + hc*8);
    *(s8v*)&t[sR * 72 + hc * 8] = v;
  }
  __syncthreads();
  for (int it = 0; it < 2; ++it) {
    int c = it * 256 + tid;
    int hd = c >> 3, sc = c & 7;
    s8v v;
    for (int j = 0; j < 8; ++j) v[j] = t[(sc*8 + j) * 72 + hd];
    *(s8v*)(Vt + (size_t)(bh*64 + hd) * S_ + s0 + sc*8) = v;
  }
}

// ---------------- flash attention v4: q-tile 64, 256 thr, 2 blocks/CU ------
// 4 waves x 16 q rows; k-tile 64 (2 ko subtiles). Grid (bh, qt): same-bh
// blocks land on one XCD (linear = bh + 16*qt, %8 = bh%8) -> K/V L2-local.
// Two blocks/CU give two independent barrier domains: one block's drain
// overlaps the other's compute (1-block/CU could not express this).
__global__ __launch_bounds__(256) void flash_kernel(
    const short* __restrict__ QKV, const short* __restrict__ Vt,
    const float* __restrict__ tabT, short* __restrict__ AO)
{
  __shared__ __attribute__((aligned(16))) short sQ[2 * 64 * 40];      // [hc][q64][40]
  __shared__ __attribute__((aligned(16))) short sK[2 * 2 * 32 * 40];  // [ko][hc][kk][40]
  __shared__ __attribute__((aligned(16))) short sV[2 * 64 * 40];      // [ko][hd][40]
  __shared__ __attribute__((aligned(16))) short sP[4 * 2 * 16 * 40];  // [w][ko][q][40]
  __shared__ float sBias[128];
  __shared__ float sRow[4 * 16];

  const int tid = threadIdx.x;
  const int w = tid >> 6, lane = tid & 63;
  const int col = lane & 15, quad = lane >> 4;
  const int bh = blockIdx.x, qt = blockIdx.y;
  const int b = bh >> 3, h = bh & 7;
  const int q0 = qt * 64;
  const int wq = w * 16;
  const float scale = 0.125f;
  const int nkt = S_ / 64;
  const float* tabh = tabT + (size_t)h * NREL_;

  // stage Q tile (8 KB) into padded LDS via registers
  for (int j = 0; j < 2; ++j) {
    int Lc = j * 256 + tid;
    int c4q = Lc & 3, q = (Lc >> 2) & 63, hc = Lc >> 8;
    *(int4*)&sQ[hc*2560 + q*40 + c4q*8] =
      *(const int4*)(QKV + (size_t)(b*S_ + q0 + q) * 1536 + h*64 + hc*32 + c4q*8);
  }

  // K/V prefetch pointers: r64 = row 0..63, each thread stages 2 int4 K + 2 int4 V
  const int c4 = tid & 3, r64 = tid >> 2;
  const short* gK = QKV + (size_t)(b*S_ + r64) * 1536 + 512 + h*64 + c4*8;  // +32 = hc1
  short* dK = &sK[(r64 >> 5)*2560 + (r64 & 31)*40 + c4*8];                  // +1280 = hc1
  const short* gV = Vt + (size_t)(bh*64 + r64) * S_ + c4*8;                 // +32 = ko1
  short* dV = &sV[r64*40 + c4*8];                                           // +2560 = ko1

  int4 rk0 = *(const int4*)gK;
  int4 rk1 = *(const int4*)(gK + 32);
  int4 rv0 = *(const int4*)gV;
  int4 rv1 = *(const int4*)(gV + 32);
  float rbias = (tid < 128) ? tabh[0 - q0 - 63 + OFF_ + tid] : 0.0f;

  s8v bQ[2];
  float lsum = 0.0f;
  f4v o[4] = {};

  for (int kt = 0; kt < nkt; ++kt) {
    __syncthreads();                       // A: drains prev compute + prefetch (vmcnt)
    *(int4*)dK = rk0;
    *(int4*)(dK + 1280) = rk1;
    *(int4*)dV = rv0;
    *(int4*)(dV + 2560) = rv1;
    if (tid < 128) sBias[tid] = rbias;
    __syncthreads();                       // B: lgkm drain only
    if (kt == 0) {
      bQ[0] = *(const s8v*)&sQ[0*2560 + (wq + col)*40 + quad*8];
      bQ[1] = *(const s8v*)&sQ[1*2560 + (wq + col)*40 + quad*8];
    }
    if (kt + 1 < nkt) {                    // issued AFTER barrier B: flies over compute
      const short* gKn = gK + (size_t)(kt + 1) * 64 * 1536;
      rk0 = *(const int4*)gKn;
      rk1 = *(const int4*)(gKn + 32);
      const short* gVn = gV + (kt + 1) * 64;
      rv0 = *(const int4*)gVn;
      rv1 = *(const int4*)(gVn + 32);
      if (tid < 128) rbias = tabh[(kt + 1)*64 - q0 - 63 + OFF_ + tid];
    }

    for (int ko = 0; ko < 2; ++ko) {
      // S^T = K Q^T : lane holds S^T[kk = mt*16+quad*4+r][q = wq+col]
      f4v st[2] = {};
      for (int mt = 0; mt < 2; ++mt) {
        s8v aK0 = *(const s8v*)&sK[ko*2560 + (mt*16 + col)*40 + quad*8];
        s8v aK1 = *(const s8v*)&sK[ko*2560 + 1280 + (mt*16 + col)*40 + quad*8];
        st[mt] = __builtin_amdgcn_mfma_f32_16x16x32_bf16(aK0, bQ[0], st[mt], 0, 0, 0);
        st[mt] = __builtin_amdgcn_mfma_f32_16x16x32_bf16(aK1, bQ[1], st[mt], 0, 0, 0);
      }
      // softmax: p = exp(s*scale + bias); single lsum (all p share q=wq+col)
      for (int mt = 0; mt < 2; ++mt) {
        int ib0 = ko*32 + mt*16 + quad*4 + 63 - wq - col;
        float p0 = __expf(st[mt][0]*scale + sBias[ib0 + 0]);
        float p1 = __expf(st[mt][1]*scale + sBias[ib0 + 1]);
        float p2 = __expf(st[mt][2]*scale + sBias[ib0 + 2]);
        float p3 = __expf(st[mt][3]*scale + sBias[ib0 + 3]);
        lsum += (p0 + p1) + (p2 + p3);
        int2 pk;
        pk.x = (int)((unsigned)(unsigned short)f2bf(p0) | ((unsigned)(unsigned short)f2bf(p1) << 16));
        pk.y = (int)((unsigned)(unsigned short)f2bf(p2) | ((unsigned)(unsigned short)f2bf(p3) << 16));
        *(int2*)&sP[w*1280 + ko*640 + col*40 + mt*16 + quad*4] = pk;
      }
      // O += P V   (per-wave sP; DS in-order within wave)
      s8v aP = *(const s8v*)&sP[w*1280 + ko*640 + col*40 + quad*8];
      for (int nt = 0; nt < 4; ++nt) {
        s8v bv = *(const s8v*)&sV[ko*2560 + (nt*16 + col)*40 + quad*8];
        o[nt] = __builtin_amdgcn_mfma_f32_16x16x32_bf16(aP, bv, o[nt], 0, 0, 0);
      }
    }
  }

  lsum += __shfl_xor(lsum, 16);
  lsum += __shfl_xor(lsum, 32);
  if (lane < 16) sRow[w*16 + lane] = lsum;
  float rs[4];
  for (int r = 0; r < 4; ++r) rs[r] = sRow[w*16 + quad*4 + r];
  for (int nt = 0; nt < 4; ++nt)
    for (int r = 0; r < 4; ++r) {
      float v = o[nt][r] / rs[r];
      size_t m = (size_t)(b*S_ + q0 + wq + quad*4 + r);
      AO[m * 512 + h*64 + nt*16 + col] = f2bf(v);
    }
}

// ===========================================================================
extern "C" void kernel_launch(void* const* d_in, const int* in_sizes, int n_in,
                              void* d_out, int out_size, void* d_ws, size_t ws_size,
                              hipStream_t stream)
{
  const float* x    = (const float*)d_in[0];
  const float* f0   = (const float*)d_in[1];
  const float* sp   = (const float*)d_in[2];
  const float* ap   = (const float*)d_in[3];
  const float* spk  = (const float*)d_in[4];
  const float* Wf0  = (const float*)d_in[5];  const float* bf0  = (const float*)d_in[6];
  const float* Wsp  = (const float*)d_in[7];  const float* bsp  = (const float*)d_in[8];
  const float* Wap  = (const float*)d_in[9];  const float* bap  = (const float*)d_in[10];
  const float* Wspk = (const float*)d_in[11]; const float* bspk = (const float*)d_in[12];
  const float* Wq   = (const float*)d_in[13]; const float* bq   = (const float*)d_in[14];
  const float* Wk   = (const float*)d_in[15]; const float* bk   = (const float*)d_in[16];
  const float* Wv   = (const float*)d_in[17]; const float* bv   = (const float*)d_in[18];
  const float* Wo   = (const float*)d_in[19]; const float* bo   = (const float*)d_in[20];
  const float* ln1g = (const float*)d_in[21]; const float* ln1b = (const float*)d_in[22];
  const float* ln2g = (const float*)d_in[23]; const float* ln2b = (const float*)d_in[24];
  const float* W1   = (const float*)d_in[25]; const float* b1   = (const float*)d_in[26];
  const float* W2   = (const float*)d_in[27]; const float* b2   = (const float*)d_in[28];
  const float* tab  = (const float*)d_in[29];
  const float* gfin = (const float*)d_in[30]; const float* bfin = (const float*)d_in[31];

  char* p = (char*)d_ws;
  auto alloc = [&](size_t bytes) { char* r = p; p += (bytes + 255) & ~(size_t)255; return r; };
  short* WqkvT = (short*)alloc((size_t)L_ * 1536 * 512 * 2);
  short* WoT   = (short*)alloc((size_t)L_ * 512 * 512 * 2);
  short* W1T   = (short*)alloc((size_t)L_ * 2048 * 512 * 2);
  short* W2T   = (short*)alloc((size_t)L_ * 512 * 2048 * 2);
  float* bqkv  = (float*)alloc((size_t)L_ * 1536 * 4);
  float* X     = (float*)alloc((size_t)M_ * D_ * 4);
  short* Hb    = (short*)alloc((size_t)M_ * D_ * 2);
  short* AO    = (short*)alloc((size_t)M_ * D_ * 2);
  short* QKVb  = (short*)alloc((size_t)M_ * 1536 * 2);
  short* VtG   = (short*)alloc((size_t)B_ * H_ * HD_ * S_ * 2);
  short* H1b   = QKVb;  // alias: FFN hidden (M,F) reuses QKVb+VtG region (exactly 16 MB)
  float* sproj = (float*)alloc((size_t)B_ * D_ * 4);
  float* tabT  = (float*)alloc((size_t)L_ * H_ * NREL_ * 4);

  dim3 b256(256);
  dim3 tb(32, 8);
  packb_kernel<<<dim3((L_*1536 + 255)/256), b256, 0, stream>>>(bq, bk, bv, bqkv);
  tabt_kernel<<<dim3((L_*H_*NREL_ + 255)/256), b256, 0, stream>>>(tab, tabT);
  transpose_kernel<<<dim3(16, 16, L_), tb, 0, stream>>>(Wq, WqkvT, 512, 512, 512*512, 1536*512, 0);
  transpose_kernel<<<dim3(16, 16, L_), tb, 0, stream>>>(Wk, WqkvT, 512, 512, 512*512, 1536*512, 512);
  transpose_kernel<<<dim3(16, 16, L_), tb, 0, stream>>>(Wv, WqkvT, 512, 512, 512*512, 1536*512, 1024);
  transpose_kernel<<<dim3(16, 16, L_), tb, 0, stream>>>(Wo, WoT, 512, 512, 512*512, 512*512, 0);
  transpose_kernel<<<dim3(64, 16, L_), tb, 0, stream>>>(W1, W1T, 512, 2048, 512*2048, 2048*512, 0);
  transpose_kernel<<<dim3(16, 64, L_), tb, 0, stream>>>(W2, W2T, 2048, 512, 2048*512, 512*2048, 0);
  spk_kernel<<<dim3(B_, 8), b256, 0, stream>>>(spk, Wspk, bspk, sproj);
  prologue_kernel<<<dim3(M_), b256, 0, stream>>>(x, f0, sp, ap, Wf0, bf0, Wsp, bsp, Wap, bap, sproj, X);

  for (int l = 0; l < L_; ++l) {
    ln_kernel<<<dim3(M_), b256, 0, stream>>>(X, ln1g + l*D_, ln1b + l*D_, Hb, nullptr, 0);
    gemm_qkv_kernel<<<dim3(24, 32, 1), b256, 0, stream>>>(
        Hb, WqkvT + (size_t)l*1536*512, bqkv + l*1536, nullptr, QKVb);
    vtrans_kernel<<<dim3(S_/64, B_*H_), b256, 0, stream>>>(QKVb, VtG);
    flash_kernel<<<dim3(B_*H_, S_/64), b256, 0, stream>>>(QKVb, VtG, tabT + (size_t)l*H_*NREL_, AO);
    gemm_o_kernel<<<dim3(8, 32, 4), b256, 0, stream>>>(
        AO, WoT + (size_t)l*512*512, bo + l*D_, X, nullptr);
    ln_kernel<<<dim3(M_), b256, 0, stream>>>(X, ln2g + l*D_, ln2b + l*D_, Hb, nullptr, 0);
    gemm_ffn1_kernel<<<dim3(32, 32, 1), b256, 0, stream>>>(
        Hb, W1T + (size_t)l*2048*512, b1 + l*F_, nullptr, H1b);
    gemm_ffn2_kernel<<<dim3(8, 32, 4), b256, 0, stream>>>(
        H1b, W2T + (size_t)l*512*2048, b2 + l*D_, X, nullptr);
  }
  ln_kernel<<<dim3(M_), b256, 0, stream>>>(X, gfin, bfin, nullptr, (float*)d_out, 1);
}

// Round 10
// 1141.224 us; speedup vs baseline: 1.0358x; 1.0358x over previous
//
#include <hip/hip_runtime.h>
#include <hip/hip_bf16.h>

#define B_ 2
#define S_ 2048
#define D_ 512
#define H_ 8
#define L_ 6
#define F_ 2048
#define HD_ 64
#define M_ 4096
#define OFF_ 4999
#define NREL_ 9999

typedef short s8v __attribute__((ext_vector_type(8)));
typedef float f4v __attribute__((ext_vector_type(4)));

enum { MODE_BF16 = 0, MODE_RES = 1, MODE_GELU = 2 };

__device__ __forceinline__ short f2bf(float f) {
  unsigned u = __float_as_uint(f);
  unsigned r = (u + 0x7fffu + ((u >> 16) & 1u)) >> 16;
  return (short)r;
}

__device__ __forceinline__ float exp2fast(float x) {
  float r;
  asm("v_exp_f32 %0, %1" : "=v"(r) : "v"(x));
  return r;
}

__device__ __forceinline__ void gload16(const void* g, const void* l) {
  __builtin_amdgcn_global_load_lds((const __attribute__((address_space(1))) unsigned int*)g,
                                   (__attribute__((address_space(3))) unsigned int*)l,
                                   16, 0, 0);
}

// ---------------- weight transpose: src fp32 (K,N) -> dst bf16 (N,K) -------
__global__ void transpose_kernel(const float* __restrict__ src, short* __restrict__ dst,
                                 int K, int N, long srcBS, long dstBS, int rowOff)
{
  __shared__ float t[32][33];
  int tx = threadIdx.x, ty = threadIdx.y;  // block (32,8)
  int n0 = blockIdx.x * 32, k0 = blockIdx.y * 32, l = blockIdx.z;
  const float* s = src + (size_t)l * srcBS;
  short* d = dst + (size_t)l * dstBS;
  for (int j = 0; j < 4; ++j)
    t[ty + j*8][tx] = s[(size_t)(k0 + ty + j*8) * N + n0 + tx];
  __syncthreads();
  for (int j = 0; j < 4; ++j)
    d[(size_t)(rowOff + n0 + ty + j*8) * K + k0 + tx] = f2bf(t[tx][ty + j*8]);
}

__global__ void packb_kernel(const float* __restrict__ bq, const float* __restrict__ bk,
                             const float* __restrict__ bv, float* __restrict__ bqkv)
{
  int i = blockIdx.x * 256 + threadIdx.x;
  if (i >= L_ * 1536) return;
  int l = i / 1536, j = i % 1536;
  float v = (j < 512) ? bq[l*512 + j] : (j < 1024) ? bk[l*512 + j - 512] : bv[l*512 + j - 1024];
  bqkv[i] = v;
}

// ---- bias table transpose + pre-scale by log2(e): exp2-domain softmax -----
__global__ void tabt_kernel(const float* __restrict__ tab, float* __restrict__ tabT)
{
  int i = blockIdx.x * 256 + threadIdx.x;
  if (i >= L_ * H_ * NREL_) return;
  int l = i / (H_ * NREL_), rem = i % (H_ * NREL_);
  int h = rem / NREL_, idx = rem % NREL_;
  tabT[i] = tab[((size_t)l * NREL_ + idx) * H_ + h] * 1.44269504f;
}

// ---------------- spk_emb @ Wspk + bspk: grid (B_, 8), k-split + LDS reduce -
__global__ __launch_bounds__(256) void spk_kernel(const float* __restrict__ spk,
                                                  const float* __restrict__ Wspk,
                                                  const float* __restrict__ bspk,
                                                  float* __restrict__ sproj)
{
  __shared__ float red[4][64];
  int b = blockIdx.x, nb = blockIdx.y;
  int dl = threadIdx.x & 63, kc = threadIdx.x >> 6;
  int d = nb * 64 + dl;
  const float* sprow = spk + b * D_;
  float a0 = 0.f, a1 = 0.f;
  int kbeg = kc * 128;
  for (int k = kbeg; k < kbeg + 128; k += 2) {
    a0 += sprow[k]     * Wspk[(size_t)k * D_ + d];
    a1 += sprow[k + 1] * Wspk[(size_t)(k + 1) * D_ + d];
  }
  red[kc][dl] = a0 + a1;
  __syncthreads();
  if (kc == 0)
    sproj[b*D_ + d] = red[0][dl] + red[1][dl] + red[2][dl] + red[3][dl] + bspk[d];
}

// ---------------- prologue: x + PE + cond encodings -> X fp32 --------------
__global__ __launch_bounds__(256) void prologue_kernel(
    const float* __restrict__ x, const float* __restrict__ f0, const float* __restrict__ sp,
    const float* __restrict__ ap, const float* __restrict__ Wf0, const float* __restrict__ bf0,
    const float* __restrict__ Wsp, const float* __restrict__ bsp,
    const float* __restrict__ Wap, const float* __restrict__ bap,
    const float* __restrict__ sproj, float* __restrict__ X)
{
  int row = blockIdx.x, tid = threadIdx.x;
  int b = row >> 11, s = row & 2047;
  float vf0 = f0[row], vsp = sp[row], vap = ap[row];
  for (int j = 0; j < 2; ++j) {
    int d = tid + j * 256;
    int i = d >> 1;
    float div = expf((float)(2*i) * -0.01798894603f);  // -ln(10000)/512
    float arg = (float)s * div;
    float pe = (d & 1) ? cosf(arg) : sinf(arg);
    float v = x[(size_t)row*D_ + d] + pe
            + vf0*Wf0[d] + bf0[d] + vsp*Wsp[d] + bsp[d] + vap*Wap[d] + bap[d]
            + sproj[b*D_ + d];
    X[(size_t)row*D_ + d] = v;
  }
}

// ---------------- layernorm: X fp32 row -> bf16 (or fp32 final) ------------
__global__ __launch_bounds__(256) void ln_kernel(
    const float* __restrict__ X, const float* __restrict__ g, const float* __restrict__ bta,
    short* __restrict__ outB, float* __restrict__ outF, int f32out)
{
  __shared__ float red[8];
  int row = blockIdx.x, tid = threadIdx.x;
  const float* xr = X + (size_t)row * D_;
  float v0 = xr[tid], v1 = xr[tid + 256];
  float s = v0 + v1, q = v0*v0 + v1*v1;
  for (int off = 1; off < 64; off <<= 1) { s += __shfl_xor(s, off); q += __shfl_xor(q, off); }
  int w = tid >> 6;
  if ((tid & 63) == 0) { red[w*2] = s; red[w*2 + 1] = q; }
  __syncthreads();
  s = red[0] + red[2] + red[4] + red[6];
  q = red[1] + red[3] + red[5] + red[7];
  float mean = s * (1.0f / D_);
  float var = q * (1.0f / D_) - mean * mean;
  float rstd = rsqrtf(var + 1e-5f);
  float o0 = (v0 - mean) * rstd * g[tid] + bta[tid];
  float o1 = (v1 - mean) * rstd * g[tid + 256] + bta[tid + 256];
  if (f32out) {
    outF[(size_t)row*D_ + tid] = o0; outF[(size_t)row*D_ + tid + 256] = o1;
  } else {
    outB[(size_t)row*D_ + tid] = f2bf(o0); outB[(size_t)row*D_ + tid + 256] = f2bf(o1);
  }
}

// ---------------- bf16 MFMA GEMM (round-6 proven DMA K-loop) ---------------
// NOTE (round-7 lesson): register-path prefetch of 6 int4/thread spilled to
// scratch -> DMA staging only. For MODE_BF16 (QKV) the Q columns (n0<512) are
// pre-scaled by 0.125*log2(e) so flash softmax runs in the exp2 domain.
template<int MODE>
__device__ __forceinline__ void gemm_body(
    const short* __restrict__ A, const short* __restrict__ Wt,
    const float* __restrict__ bias, int K, int N,
    float* outF, short* outB)
{
  __shared__ short sA[2][4096];  // [panel][128 rows][32 k]
  __shared__ short sB[2][2048];  // [panel][64 rows][32 k]
  const int tid = threadIdx.x;
  const int w = tid >> 6, lane = tid & 63;
  const int col = lane & 15, quad = lane >> 4;
  const int n0 = blockIdx.x * 64, m0 = blockIdx.y * 128;
  const int z = blockIdx.z;
  const int Ksub = K / gridDim.z;
  const int kbase = z * Ksub;
  const int nkt = Ksub >> 6;

  const int rowT = tid >> 2, kcA = tid & 3;
  const size_t kc8 = kcA * 8;

  f4v acc[2][4] = {};
  for (int kt = 0; kt < nkt; ++kt) {
    const int k0 = kbase + kt * 64;
    __syncthreads();
    for (int p = 0; p < 2; ++p) {
      gload16(A + (size_t)(m0 + rowT) * K + k0 + p*32 + kc8,       &sA[p][(w*16) * 32]);
      gload16(A + (size_t)(m0 + 64 + rowT) * K + k0 + p*32 + kc8,  &sA[p][(64 + w*16) * 32]);
      gload16(Wt + (size_t)(n0 + rowT) * K + k0 + p*32 + kc8,      &sB[p][(w*16) * 32]);
    }
    __syncthreads();
    for (int p = 0; p < 2; ++p) {
      s8v af[2], bfr[4];
      for (int mt = 0; mt < 2; ++mt)
        af[mt] = *(const s8v*)&sA[p][(w*32 + mt*16 + col) * 32 + quad * 8];
      for (int nt = 0; nt < 4; ++nt)
        bfr[nt] = *(const s8v*)&sB[p][(nt*16 + col) * 32 + quad * 8];
      for (int mt = 0; mt < 2; ++mt)
        for (int nt = 0; nt < 4; ++nt)
          acc[mt][nt] = __builtin_amdgcn_mfma_f32_16x16x32_bf16(af[mt], bfr[nt], acc[mt][nt], 0, 0, 0);
    }
  }

  const float qsc = (MODE == MODE_BF16 && n0 < 512) ? 0.18033688f : 1.0f;  // 0.125*log2e
  float bz[4];
  for (int nt = 0; nt < 4; ++nt)
    bz[nt] = (z == 0) ? bias[n0 + nt*16 + col] : 0.0f;
  for (int mt = 0; mt < 2; ++mt) {
    int mbase = m0 + w*32 + mt*16 + quad*4;
    for (int nt = 0; nt < 4; ++nt) {
      int n = n0 + nt*16 + col;
      for (int r = 0; r < 4; ++r) {
        float v = acc[mt][nt][r] + bz[nt];
        size_t idx = (size_t)(mbase + r) * N + n;
        if (MODE == MODE_RES) {
          atomicAdd(outF + idx, v);
        } else if (MODE == MODE_GELU) {
          outB[idx] = f2bf(0.5f * v * (1.0f + erff(v * 0.70710678118f)));
        } else {
          outB[idx] = f2bf(v * qsc);
        }
      }
    }
  }
}

__global__ __launch_bounds__(256) void gemm_qkv_kernel(
    const short* __restrict__ A, const short* __restrict__ Wt,
    const float* __restrict__ bias, float* outF, short* outB)
{ gemm_body<MODE_BF16>(A, Wt, bias, 512, 1536, outF, outB); }

__global__ __launch_bounds__(256) void gemm_o_kernel(
    const short* __restrict__ A, const short* __restrict__ Wt,
    const float* __restrict__ bias, float* outF, short* outB)
{ gemm_body<MODE_RES>(A, Wt, bias, 512, 512, outF, outB); }

__global__ __launch_bounds__(256) void gemm_ffn1_kernel(
    const short* __restrict__ A, const short* __restrict__ Wt,
    const float* __restrict__ bias, float* outF, short* outB)
{ gemm_body<MODE_GELU>(A, Wt, bias, 512, 2048, outF, outB); }

__global__ __launch_bounds__(256) void gemm_ffn2_kernel(
    const short* __restrict__ A, const short* __restrict__ Wt,
    const float* __restrict__ bias, float* outF, short* outB)
{ gemm_body<MODE_RES>(A, Wt, bias, 2048, 512, outF, outB); }

// ---------------- V transpose: QKV V-part (b,s,h,hd) -> Vt (b,h,hd,s) ------
__global__ __launch_bounds__(256) void vtrans_kernel(const short* __restrict__ QKV,
                                                     short* __restrict__ Vt)
{
  __shared__ short t[64 * 72];
  int tid = threadIdx.x;
  int s0 = blockIdx.x * 64, bh = blockIdx.y;
  int b = bh >> 3, h = bh & 7;
  for (int it = 0; it < 2; ++it) {
    int c = it * 256 + tid;
    int sR = c >> 3, hc = c & 7;
    s8v v = *(const s8v*)(QKV + (size_t)(b*S_ + s0 + sR) * 1536 + 1024 + h*64 + hc*8);
    *(s8v*)&t[sR * 72 + hc * 8] = v;
  }
  __syncthreads();
  for (int it = 0; it < 2; ++it) {
    int c = it * 256 + tid;
    int hd = c >> 3, sc = c & 7;
    s8v v;
    for (int j = 0; j < 8; ++j) v[j] = t[(sc*8 + j) * 72 + hd];
    *(s8v*)(Vt + (size_t)(bh*64 + hd) * S_ + s0 + sc*8) = v;
  }
}

// ---------------- flash attention v5: q128/512thr (v3) + XCD swizzle -------
// grid (bh, qt): linear id = bh + 16*qt -> XCD = bh%8 -> K/V stay L2-local
// (round-9 measured FETCH 35->6.3 MB). Softmax in exp2 domain: Q pre-scaled
// 0.125*log2e (QKV epilogue), bias pre-scaled log2e (tabt) -> p = v_exp(s+b).
// P pack: round-half-up high-half extraction (5 ops/pair vs ~10 RTNE).
__global__ __launch_bounds__(512) void flash_kernel(
    const short* __restrict__ QKV, const short* __restrict__ Vt,
    const float* __restrict__ tabT, short* __restrict__ AO)
{
  __shared__ __attribute__((aligned(16))) short sQ[2 * 128 * 40];     // [hc][q][40]
  __shared__ __attribute__((aligned(16))) short sK[2 * 2 * 32 * 40];  // [ko][hc][kk][40]
  __shared__ __attribute__((aligned(16))) short sV[2 * 64 * 40];      // [ko][hd][40]
  __shared__ __attribute__((aligned(16))) short sP[8 * 2 * 16 * 40];  // [w][ko][q][40]
  __shared__ float sBias[192];
  __shared__ float sRow[8 * 16];

  const int tid = threadIdx.x;
  const int w = tid >> 6, lane = tid & 63;
  const int col = lane & 15, quad = lane >> 4;
  const int bh = blockIdx.x, qt = blockIdx.y;
  const int b = bh >> 3, h = bh & 7;
  const int q0 = qt * 128;
  const int wq = w * 16;
  const int nkt = S_ / 64;
  const float* tabh = tabT + (size_t)h * NREL_;

  for (int j = 0; j < 2; ++j) {
    int Lc = j * 512 + tid;
    int c4q = Lc & 3, q = (Lc >> 2) & 127, hc = Lc >> 9;
    *(int4*)&sQ[hc*5120 + q*40 + c4q*8] =
      *(const int4*)(QKV + (size_t)(b*S_ + q0 + q) * 1536 + h*64 + hc*32 + c4q*8);
  }

  const int c4 = tid & 3;
  const int kK = (tid >> 2) & 63, hcK = tid >> 8;
  const short* gK = QKV + (size_t)(b*S_ + kK) * 1536 + 512 + h*64 + hcK*32 + c4*8;
  short* dK = &sK[(kK >> 5)*2560 + hcK*1280 + (kK & 31)*40 + c4*8];
  const int c8 = tid & 7, hdV = tid >> 3;
  const short* gV = Vt + (size_t)(bh*64 + hdV) * S_ + c8*8;
  short* dV = &sV[(c8 >> 2)*2560 + hdV*40 + (c8 & 3)*8];

  int4 rk = *(const int4*)gK;
  int4 rv = *(const int4*)gV;
  float rbias = (tid < 192) ? tabh[0 - q0 - 127 + OFF_ + tid] : 0.0f;

  s8v bQ[2];
  float lsum = 0.0f;
  f4v o[4] = {};

  for (int kt = 0; kt < nkt; ++kt) {
    __syncthreads();
    *(int4*)dK = rk;
    *(int4*)dV = rv;
    if (tid < 192) sBias[tid] = rbias;
    __syncthreads();
    if (kt == 0) {
      bQ[0] = *(const s8v*)&sQ[0*5120 + (wq + col)*40 + quad*8];
      bQ[1] = *(const s8v*)&sQ[1*5120 + (wq + col)*40 + quad*8];
    }
    if (kt + 1 < nkt) {
      rk = *(const int4*)(gK + (size_t)(kt + 1) * 64 * 1536);
      rv = *(const int4*)(gV + (kt + 1) * 64);
      if (tid < 192) rbias = tabh[(kt + 1)*64 - q0 - 127 + OFF_ + tid];
    }

    for (int ko = 0; ko < 2; ++ko) {
      f4v st[2] = {};
      for (int mt = 0; mt < 2; ++mt) {
        s8v aK0 = *(const s8v*)&sK[ko*2560 + 0*1280 + (mt*16 + col)*40 + quad*8];
        s8v aK1 = *(const s8v*)&sK[ko*2560 + 1*1280 + (mt*16 + col)*40 + quad*8];
        st[mt] = __builtin_amdgcn_mfma_f32_16x16x32_bf16(aK0, bQ[0], st[mt], 0, 0, 0);
        st[mt] = __builtin_amdgcn_mfma_f32_16x16x32_bf16(aK1, bQ[1], st[mt], 0, 0, 0);
      }
      for (int mt = 0; mt < 2; ++mt) {
        int ib0 = ko*32 + mt*16 + quad*4 + 127 - wq - col;
        float p0 = exp2fast(st[mt][0] + sBias[ib0 + 0]);
        float p1 = exp2fast(st[mt][1] + sBias[ib0 + 1]);
        float p2 = exp2fast(st[mt][2] + sBias[ib0 + 2]);
        float p3 = exp2fast(st[mt][3] + sBias[ib0 + 3]);
        lsum += (p0 + p1) + (p2 + p3);
        unsigned u0 = __float_as_uint(p0) + 0x8000u;
        unsigned u1 = __float_as_uint(p1) + 0x8000u;
        unsigned u2 = __float_as_uint(p2) + 0x8000u;
        unsigned u3 = __float_as_uint(p3) + 0x8000u;
        int2 pk;
        pk.x = (int)((u0 >> 16) | (u1 & 0xffff0000u));
        pk.y = (int)((u2 >> 16) | (u3 & 0xffff0000u));
        *(int2*)&sP[w*1280 + ko*640 + col*40 + mt*16 + quad*4] = pk;
      }
      s8v aP = *(const s8v*)&sP[w*1280 + ko*640 + col*40 + quad*8];
      for (int nt = 0; nt < 4; ++nt) {
        s8v bv = *(const s8v*)&sV[ko*2560 + (nt*16 + col)*40 + quad*8];
        o[nt] = __builtin_amdgcn_mfma_f32_16x16x32_bf16(aP, bv, o[nt], 0, 0, 0);
      }
    }
  }

  lsum += __shfl_xor(lsum, 16);
  lsum += __shfl_xor(lsum, 32);
  if (lane < 16) sRow[w*16 + lane] = lsum;
  float rs[4];
  for (int r = 0; r < 4; ++r) rs[r] = sRow[w*16 + quad*4 + r];
  for (int nt = 0; nt < 4; ++nt)
    for (int r = 0; r < 4; ++r) {
      float v = o[nt][r] / rs[r];
      size_t m = (size_t)(b*S_ + q0 + wq + quad*4 + r);
      AO[m * 512 + h*64 + nt*16 + col] = f2bf(v);
    }
}

// ===========================================================================
extern "C" void kernel_launch(void* const* d_in, const int* in_sizes, int n_in,
                              void* d_out, int out_size, void* d_ws, size_t ws_size,
                              hipStream_t stream)
{
  const float* x    = (const float*)d_in[0];
  const float* f0   = (const float*)d_in[1];
  const float* sp   = (const float*)d_in[2];
  const float* ap   = (const float*)d_in[3];
  const float* spk  = (const float*)d_in[4];
  const float* Wf0  = (const float*)d_in[5];  const float* bf0  = (const float*)d_in[6];
  const float* Wsp  = (const float*)d_in[7];  const float* bsp  = (const float*)d_in[8];
  const float* Wap  = (const float*)d_in[9];  const float* bap  = (const float*)d_in[10];
  const float* Wspk = (const float*)d_in[11]; const float* bspk = (const float*)d_in[12];
  const float* Wq   = (const float*)d_in[13]; const float* bq   = (const float*)d_in[14];
  const float* Wk   = (const float*)d_in[15]; const float* bk   = (const float*)d_in[16];
  const float* Wv   = (const float*)d_in[17]; const float* bv   = (const float*)d_in[18];
  const float* Wo   = (const float*)d_in[19]; const float* bo   = (const float*)d_in[20];
  const float* ln1g = (const float*)d_in[21]; const float* ln1b = (const float*)d_in[22];
  const float* ln2g = (const float*)d_in[23]; const float* ln2b = (const float*)d_in[24];
  const float* W1   = (const float*)d_in[25]; const float* b1   = (const float*)d_in[26];
  const float* W2   = (const float*)d_in[27]; const float* b2   = (const float*)d_in[28];
  const float* tab  = (const float*)d_in[29];
  const float* gfin = (const float*)d_in[30]; const float* bfin = (const float*)d_in[31];

  char* p = (char*)d_ws;
  auto alloc = [&](size_t bytes) { char* r = p; p += (bytes + 255) & ~(size_t)255; return r; };
  short* WqkvT = (short*)alloc((size_t)L_ * 1536 * 512 * 2);
  short* WoT   = (short*)alloc((size_t)L_ * 512 * 512 * 2);
  short* W1T   = (short*)alloc((size_t)L_ * 2048 * 512 * 2);
  short* W2T   = (short*)alloc((size_t)L_ * 512 * 2048 * 2);
  float* bqkv  = (float*)alloc((size_t)L_ * 1536 * 4);
  float* X     = (float*)alloc((size_t)M_ * D_ * 4);
  short* Hb    = (short*)alloc((size_t)M_ * D_ * 2);
  short* AO    = (short*)alloc((size_t)M_ * D_ * 2);
  short* QKVb  = (short*)alloc((size_t)M_ * 1536 * 2);
  short* VtG   = (short*)alloc((size_t)B_ * H_ * HD_ * S_ * 2);
  short* H1b   = QKVb;  // alias: FFN hidden (M,F) reuses QKVb+VtG region (exactly 16 MB)
  float* sproj = (float*)alloc((size_t)B_ * D_ * 4);
  float* tabT  = (float*)alloc((size_t)L_ * H_ * NREL_ * 4);

  dim3 b256(256);
  dim3 tb(32, 8);
  packb_kernel<<<dim3((L_*1536 + 255)/256), b256, 0, stream>>>(bq, bk, bv, bqkv);
  tabt_kernel<<<dim3((L_*H_*NREL_ + 255)/256), b256, 0, stream>>>(tab, tabT);
  transpose_kernel<<<dim3(16, 16, L_), tb, 0, stream>>>(Wq, WqkvT, 512, 512, 512*512, 1536*512, 0);
  transpose_kernel<<<dim3(16, 16, L_), tb, 0, stream>>>(Wk, WqkvT, 512, 512, 512*512, 1536*512, 512);
  transpose_kernel<<<dim3(16, 16, L_), tb, 0, stream>>>(Wv, WqkvT, 512, 512, 512*512, 1536*512, 1024);
  transpose_kernel<<<dim3(16, 16, L_), tb, 0, stream>>>(Wo, WoT, 512, 512, 512*512, 512*512, 0);
  transpose_kernel<<<dim3(64, 16, L_), tb, 0, stream>>>(W1, W1T, 512, 2048, 512*2048, 2048*512, 0);
  transpose_kernel<<<dim3(16, 64, L_), tb, 0, stream>>>(W2, W2T, 2048, 512, 2048*512, 512*2048, 0);
  spk_kernel<<<dim3(B_, 8), b256, 0, stream>>>(spk, Wspk, bspk, sproj);
  prologue_kernel<<<dim3(M_), b256, 0, stream>>>(x, f0, sp, ap, Wf0, bf0, Wsp, bsp, Wap, bap, sproj, X);

  for (int l = 0; l < L_; ++l) {
    ln_kernel<<<dim3(M_), b256, 0, stream>>>(X, ln1g + l*D_, ln1b + l*D_, Hb, nullptr, 0);
    gemm_qkv_kernel<<<dim3(24, 32, 1), b256, 0, stream>>>(
        Hb, WqkvT + (size_t)l*1536*512, bqkv + l*1536, nullptr, QKVb);
    vtrans_kernel<<<dim3(S_/64, B_*H_), b256, 0, stream>>>(QKVb, VtG);
    flash_kernel<<<dim3(B_*H_, S_/128), dim3(512), 0, stream>>>(QKVb, VtG, tabT + (size_t)l*H_*NREL_, AO);
    gemm_o_kernel<<<dim3(8, 32, 4), b256, 0, stream>>>(
        AO, WoT + (size_t)l*512*512, bo + l*D_, X, nullptr);
    ln_kernel<<<dim3(M_), b256, 0, stream>>>(X, ln2g + l*D_, ln2b + l*D_, Hb, nullptr, 0);
    gemm_ffn1_kernel<<<dim3(32, 32, 1), b256, 0, stream>>>(
        Hb, W1T + (size_t)l*2048*512, b1 + l*F_, nullptr, H1b);
    gemm_ffn2_kernel<<<dim3(8, 32, 4), b256, 0, stream>>>(
        H1b, W2T + (size_t)l*512*2048, b2 + l*D_, X, nullptr);
  }
  ln_kernel<<<dim3(M_), b256, 0, stream>>>(X, gfin, bfin, nullptr, (float*)d_out, 1);
}

// Round 11
// 1018.909 us; speedup vs baseline: 1.1601x; 1.1200x over previous
//
#include <hip/hip_runtime.h>
#include <hip/hip_bf16.h>

#define B_ 2
#define S_ 2048
#define D_ 512
#define H_ 8
#define L_ 6
#define F_ 2048
#define HD_ 64
#define M_ 4096
#define OFF_ 4999
#define NREL_ 9999

typedef short s8v __attribute__((ext_vector_type(8)));
typedef float f4v __attribute__((ext_vector_type(4)));

enum { MODE_BF16 = 0, MODE_RES = 1, MODE_GELU = 2 };

__device__ __forceinline__ short f2bf(float f) {
  unsigned u = __float_as_uint(f);
  unsigned r = (u + 0x7fffu + ((u >> 16) & 1u)) >> 16;
  return (short)r;
}

__device__ __forceinline__ float exp2fast(float x) {
  float r;
  asm("v_exp_f32 %0, %1" : "=v"(r) : "v"(x));
  return r;
}

__device__ __forceinline__ void gload16(const void* g, const void* l) {
  __builtin_amdgcn_global_load_lds((const __attribute__((address_space(1))) unsigned int*)g,
                                   (__attribute__((address_space(3))) unsigned int*)l,
                                   16, 0, 0);
}

// ---------------- weight transpose: src fp32 (K,N) -> dst bf16 (N,K) -------
__global__ void transpose_kernel(const float* __restrict__ src, short* __restrict__ dst,
                                 int K, int N, long srcBS, long dstBS, int rowOff)
{
  __shared__ float t[32][33];
  int tx = threadIdx.x, ty = threadIdx.y;  // block (32,8)
  int n0 = blockIdx.x * 32, k0 = blockIdx.y * 32, l = blockIdx.z;
  const float* s = src + (size_t)l * srcBS;
  short* d = dst + (size_t)l * dstBS;
  for (int j = 0; j < 4; ++j)
    t[ty + j*8][tx] = s[(size_t)(k0 + ty + j*8) * N + n0 + tx];
  __syncthreads();
  for (int j = 0; j < 4; ++j)
    d[(size_t)(rowOff + n0 + ty + j*8) * K + k0 + tx] = f2bf(t[tx][ty + j*8]);
}

__global__ void packb_kernel(const float* __restrict__ bq, const float* __restrict__ bk,
                             const float* __restrict__ bv, float* __restrict__ bqkv)
{
  int i = blockIdx.x * 256 + threadIdx.x;
  if (i >= L_ * 1536) return;
  int l = i / 1536, j = i % 1536;
  float v = (j < 512) ? bq[l*512 + j] : (j < 1024) ? bk[l*512 + j - 512] : bv[l*512 + j - 1024];
  bqkv[i] = v;
}

// ---- bias table transpose + pre-scale by log2(e): exp2-domain softmax -----
__global__ void tabt_kernel(const float* __restrict__ tab, float* __restrict__ tabT)
{
  int i = blockIdx.x * 256 + threadIdx.x;
  if (i >= L_ * H_ * NREL_) return;
  int l = i / (H_ * NREL_), rem = i % (H_ * NREL_);
  int h = rem / NREL_, idx = rem % NREL_;
  tabT[i] = tab[((size_t)l * NREL_ + idx) * H_ + h] * 1.44269504f;
}

// ---------------- spk_emb @ Wspk + bspk: grid (B_, 8), k-split + LDS reduce -
__global__ __launch_bounds__(256) void spk_kernel(const float* __restrict__ spk,
                                                  const float* __restrict__ Wspk,
                                                  const float* __restrict__ bspk,
                                                  float* __restrict__ sproj)
{
  __shared__ float red[4][64];
  int b = blockIdx.x, nb = blockIdx.y;
  int dl = threadIdx.x & 63, kc = threadIdx.x >> 6;
  int d = nb * 64 + dl;
  const float* sprow = spk + b * D_;
  float a0 = 0.f, a1 = 0.f;
  int kbeg = kc * 128;
  for (int k = kbeg; k < kbeg + 128; k += 2) {
    a0 += sprow[k]     * Wspk[(size_t)k * D_ + d];
    a1 += sprow[k + 1] * Wspk[(size_t)(k + 1) * D_ + d];
  }
  red[kc][dl] = a0 + a1;
  __syncthreads();
  if (kc == 0)
    sproj[b*D_ + d] = red[0][dl] + red[1][dl] + red[2][dl] + red[3][dl] + bspk[d];
}

// ---------------- prologue: x + PE + cond encodings -> X fp32 --------------
__global__ __launch_bounds__(256) void prologue_kernel(
    const float* __restrict__ x, const float* __restrict__ f0, const float* __restrict__ sp,
    const float* __restrict__ ap, const float* __restrict__ Wf0, const float* __restrict__ bf0,
    const float* __restrict__ Wsp, const float* __restrict__ bsp,
    const float* __restrict__ Wap, const float* __restrict__ bap,
    const float* __restrict__ sproj, float* __restrict__ X)
{
  int row = blockIdx.x, tid = threadIdx.x;
  int b = row >> 11, s = row & 2047;
  float vf0 = f0[row], vsp = sp[row], vap = ap[row];
  for (int j = 0; j < 2; ++j) {
    int d = tid + j * 256;
    int i = d >> 1;
    float div = expf((float)(2*i) * -0.01798894603f);  // -ln(10000)/512
    float arg = (float)s * div;
    float pe = (d & 1) ? cosf(arg) : sinf(arg);
    float v = x[(size_t)row*D_ + d] + pe
            + vf0*Wf0[d] + bf0[d] + vsp*Wsp[d] + bsp[d] + vap*Wap[d] + bap[d]
            + sproj[b*D_ + d];
    X[(size_t)row*D_ + d] = v;
  }
}

// ---------------- layernorm: X fp32 row -> bf16 (or fp32 final) ------------
__global__ __launch_bounds__(256) void ln_kernel(
    const float* __restrict__ X, const float* __restrict__ g, const float* __restrict__ bta,
    short* __restrict__ outB, float* __restrict__ outF, int f32out)
{
  __shared__ float red[8];
  int row = blockIdx.x, tid = threadIdx.x;
  const float* xr = X + (size_t)row * D_;
  float v0 = xr[tid], v1 = xr[tid + 256];
  float s = v0 + v1, q = v0*v0 + v1*v1;
  for (int off = 1; off < 64; off <<= 1) { s += __shfl_xor(s, off); q += __shfl_xor(q, off); }
  int w = tid >> 6;
  if ((tid & 63) == 0) { red[w*2] = s; red[w*2 + 1] = q; }
  __syncthreads();
  s = red[0] + red[2] + red[4] + red[6];
  q = red[1] + red[3] + red[5] + red[7];
  float mean = s * (1.0f / D_);
  float var = q * (1.0f / D_) - mean * mean;
  float rstd = rsqrtf(var + 1e-5f);
  float o0 = (v0 - mean) * rstd * g[tid] + bta[tid];
  float o1 = (v1 - mean) * rstd * g[tid + 256] + bta[tid + 256];
  if (f32out) {
    outF[(size_t)row*D_ + tid] = o0; outF[(size_t)row*D_ + tid + 256] = o1;
  } else {
    outB[(size_t)row*D_ + tid] = f2bf(o0); outB[(size_t)row*D_ + tid + 256] = f2bf(o1);
  }
}

// ---------------- bf16 MFMA GEMM (round-6 DMA K-loop, m-major grid) --------
// Grid: x = m-block (32, 128 rows each), y = n-block (64 cols), z = split-K.
// gridDim.x = 32 == 0 mod 8 -> all blocks sharing an A-slice (same m, any
// n/z) have linear id === m (mod 8) -> same XCD -> A is L2-local; W (smaller)
// amplifies instead. [round-10: n-major gave ffn2 FETCH=66MB vs 18MB ideal]
// NOTE (round-7 lesson): register-path prefetch spills to scratch -> DMA only.
template<int MODE>
__device__ __forceinline__ void gemm_body(
    const short* __restrict__ A, const short* __restrict__ Wt,
    const float* __restrict__ bias, int K, int N,
    float* outF, short* outB)
{
  __shared__ short sA[2][4096];  // [panel][128 rows][32 k]
  __shared__ short sB[2][2048];  // [panel][64 rows][32 k]
  const int tid = threadIdx.x;
  const int w = tid >> 6, lane = tid & 63;
  const int col = lane & 15, quad = lane >> 4;
  const int m0 = blockIdx.x * 128, n0 = blockIdx.y * 64;
  const int z = blockIdx.z;
  const int Ksub = K / gridDim.z;
  const int kbase = z * Ksub;
  const int nkt = Ksub >> 6;

  const int rowT = tid >> 2, kcA = tid & 3;
  const size_t kc8 = kcA * 8;

  f4v acc[2][4] = {};
  for (int kt = 0; kt < nkt; ++kt) {
    const int k0 = kbase + kt * 64;
    __syncthreads();
    for (int p = 0; p < 2; ++p) {
      gload16(A + (size_t)(m0 + rowT) * K + k0 + p*32 + kc8,       &sA[p][(w*16) * 32]);
      gload16(A + (size_t)(m0 + 64 + rowT) * K + k0 + p*32 + kc8,  &sA[p][(64 + w*16) * 32]);
      gload16(Wt + (size_t)(n0 + rowT) * K + k0 + p*32 + kc8,      &sB[p][(w*16) * 32]);
    }
    __syncthreads();
    for (int p = 0; p < 2; ++p) {
      s8v af[2], bfr[4];
      for (int mt = 0; mt < 2; ++mt)
        af[mt] = *(const s8v*)&sA[p][(w*32 + mt*16 + col) * 32 + quad * 8];
      for (int nt = 0; nt < 4; ++nt)
        bfr[nt] = *(const s8v*)&sB[p][(nt*16 + col) * 32 + quad * 8];
      for (int mt = 0; mt < 2; ++mt)
        for (int nt = 0; nt < 4; ++nt)
          acc[mt][nt] = __builtin_amdgcn_mfma_f32_16x16x32_bf16(af[mt], bfr[nt], acc[mt][nt], 0, 0, 0);
    }
  }

  const float qsc = (MODE == MODE_BF16 && n0 < 512) ? 0.18033688f : 1.0f;  // 0.125*log2e
  float bz[4];
  for (int nt = 0; nt < 4; ++nt)
    bz[nt] = (z == 0) ? bias[n0 + nt*16 + col] : 0.0f;
  for (int mt = 0; mt < 2; ++mt) {
    int mbase = m0 + w*32 + mt*16 + quad*4;
    for (int nt = 0; nt < 4; ++nt) {
      int n = n0 + nt*16 + col;
      for (int r = 0; r < 4; ++r) {
        float v = acc[mt][nt][r] + bz[nt];
        size_t idx = (size_t)(mbase + r) * N + n;
        if (MODE == MODE_RES) {
          atomicAdd(outF + idx, v);
        } else if (MODE == MODE_GELU) {
          outB[idx] = f2bf(0.5f * v * (1.0f + erff(v * 0.70710678118f)));
        } else {
          outB[idx] = f2bf(v * qsc);
        }
      }
    }
  }
}

__global__ __launch_bounds__(256) void gemm_qkv_kernel(
    const short* __restrict__ A, const short* __restrict__ Wt,
    const float* __restrict__ bias, float* outF, short* outB)
{ gemm_body<MODE_BF16>(A, Wt, bias, 512, 1536, outF, outB); }

__global__ __launch_bounds__(256) void gemm_o_kernel(
    const short* __restrict__ A, const short* __restrict__ Wt,
    const float* __restrict__ bias, float* outF, short* outB)
{ gemm_body<MODE_RES>(A, Wt, bias, 512, 512, outF, outB); }

__global__ __launch_bounds__(256) void gemm_ffn1_kernel(
    const short* __restrict__ A, const short* __restrict__ Wt,
    const float* __restrict__ bias, float* outF, short* outB)
{ gemm_body<MODE_GELU>(A, Wt, bias, 512, 2048, outF, outB); }

__global__ __launch_bounds__(256) void gemm_ffn2_kernel(
    const short* __restrict__ A, const short* __restrict__ Wt,
    const float* __restrict__ bias, float* outF, short* outB)
{ gemm_body<MODE_RES>(A, Wt, bias, 2048, 512, outF, outB); }

// ---------------- V transpose: QKV V-part (b,s,h,hd) -> Vt (b,h,hd,s) ------
__global__ __launch_bounds__(256) void vtrans_kernel(const short* __restrict__ QKV,
                                                     short* __restrict__ Vt)
{
  __shared__ short t[64 * 72];
  int tid = threadIdx.x;
  int s0 = blockIdx.x * 64, bh = blockIdx.y;
  int b = bh >> 3, h = bh & 7;
  for (int it = 0; it < 2; ++it) {
    int c = it * 256 + tid;
    int sR = c >> 3, hc = c & 7;
    s8v v = *(const s8v*)(QKV + (size_t)(b*S_ + s0 + sR) * 1536 + 1024 + h*64 + hc*8);
    *(s8v*)&t[sR * 72 + hc * 8] = v;
  }
  __syncthreads();
  for (int it = 0; it < 2; ++it) {
    int c = it * 256 + tid;
    int hd = c >> 3, sc = c & 7;
    s8v v;
    for (int j = 0; j < 8; ++j) v[j] = t[(sc*8 + j) * 72 + hd];
    *(s8v*)(Vt + (size_t)(bh*64 + hd) * S_ + s0 + sc*8) = v;
  }
}

// ---------------- flash attention v5 (round-10, unchanged) -----------------
__global__ __launch_bounds__(512) void flash_kernel(
    const short* __restrict__ QKV, const short* __restrict__ Vt,
    const float* __restrict__ tabT, short* __restrict__ AO)
{
  __shared__ __attribute__((aligned(16))) short sQ[2 * 128 * 40];     // [hc][q][40]
  __shared__ __attribute__((aligned(16))) short sK[2 * 2 * 32 * 40];  // [ko][hc][kk][40]
  __shared__ __attribute__((aligned(16))) short sV[2 * 64 * 40];      // [ko][hd][40]
  __shared__ __attribute__((aligned(16))) short sP[8 * 2 * 16 * 40];  // [w][ko][q][40]
  __shared__ float sBias[192];
  __shared__ float sRow[8 * 16];

  const int tid = threadIdx.x;
  const int w = tid >> 6, lane = tid & 63;
  const int col = lane & 15, quad = lane >> 4;
  const int bh = blockIdx.x, qt = blockIdx.y;
  const int b = bh >> 3, h = bh & 7;
  const int q0 = qt * 128;
  const int wq = w * 16;
  const int nkt = S_ / 64;
  const float* tabh = tabT + (size_t)h * NREL_;

  for (int j = 0; j < 2; ++j) {
    int Lc = j * 512 + tid;
    int c4q = Lc & 3, q = (Lc >> 2) & 127, hc = Lc >> 9;
    *(int4*)&sQ[hc*5120 + q*40 + c4q*8] =
      *(const int4*)(QKV + (size_t)(b*S_ + q0 + q) * 1536 + h*64 + hc*32 + c4q*8);
  }

  const int c4 = tid & 3;
  const int kK = (tid >> 2) & 63, hcK = tid >> 8;
  const short* gK = QKV + (size_t)(b*S_ + kK) * 1536 + 512 + h*64 + hcK*32 + c4*8;
  short* dK = &sK[(kK >> 5)*2560 + hcK*1280 + (kK & 31)*40 + c4*8];
  const int c8 = tid & 7, hdV = tid >> 3;
  const short* gV = Vt + (size_t)(bh*64 + hdV) * S_ + c8*8;
  short* dV = &sV[(c8 >> 2)*2560 + hdV*40 + (c8 & 3)*8];

  int4 rk = *(const int4*)gK;
  int4 rv = *(const int4*)gV;
  float rbias = (tid < 192) ? tabh[0 - q0 - 127 + OFF_ + tid] : 0.0f;

  s8v bQ[2];
  float lsum = 0.0f;
  f4v o[4] = {};

  for (int kt = 0; kt < nkt; ++kt) {
    __syncthreads();
    *(int4*)dK = rk;
    *(int4*)dV = rv;
    if (tid < 192) sBias[tid] = rbias;
    __syncthreads();
    if (kt == 0) {
      bQ[0] = *(const s8v*)&sQ[0*5120 + (wq + col)*40 + quad*8];
      bQ[1] = *(const s8v*)&sQ[1*5120 + (wq + col)*40 + quad*8];
    }
    if (kt + 1 < nkt) {
      rk = *(const int4*)(gK + (size_t)(kt + 1) * 64 * 1536);
      rv = *(const int4*)(gV + (kt + 1) * 64);
      if (tid < 192) rbias = tabh[(kt + 1)*64 - q0 - 127 + OFF_ + tid];
    }

    for (int ko = 0; ko < 2; ++ko) {
      f4v st[2] = {};
      for (int mt = 0; mt < 2; ++mt) {
        s8v aK0 = *(const s8v*)&sK[ko*2560 + 0*1280 + (mt*16 + col)*40 + quad*8];
        s8v aK1 = *(const s8v*)&sK[ko*2560 + 1*1280 + (mt*16 + col)*40 + quad*8];
        st[mt] = __builtin_amdgcn_mfma_f32_16x16x32_bf16(aK0, bQ[0], st[mt], 0, 0, 0);
        st[mt] = __builtin_amdgcn_mfma_f32_16x16x32_bf16(aK1, bQ[1], st[mt], 0, 0, 0);
      }
      for (int mt = 0; mt < 2; ++mt) {
        int ib0 = ko*32 + mt*16 + quad*4 + 127 - wq - col;
        float p0 = exp2fast(st[mt][0] + sBias[ib0 + 0]);
        float p1 = exp2fast(st[mt][1] + sBias[ib0 + 1]);
        float p2 = exp2fast(st[mt][2] + sBias[ib0 + 2]);
        float p3 = exp2fast(st[mt][3] + sBias[ib0 + 3]);
        lsum += (p0 + p1) + (p2 + p3);
        unsigned u0 = __float_as_uint(p0) + 0x8000u;
        unsigned u1 = __float_as_uint(p1) + 0x8000u;
        unsigned u2 = __float_as_uint(p2) + 0x8000u;
        unsigned u3 = __float_as_uint(p3) + 0x8000u;
        int2 pk;
        pk.x = (int)((u0 >> 16) | (u1 & 0xffff0000u));
        pk.y = (int)((u2 >> 16) | (u3 & 0xffff0000u));
        *(int2*)&sP[w*1280 + ko*640 + col*40 + mt*16 + quad*4] = pk;
      }
      s8v aP = *(const s8v*)&sP[w*1280 + ko*640 + col*40 + quad*8];
      for (int nt = 0; nt < 4; ++nt) {
        s8v bv = *(const s8v*)&sV[ko*2560 + (nt*16 + col)*40 + quad*8];
        o[nt] = __builtin_amdgcn_mfma_f32_16x16x32_bf16(aP, bv, o[nt], 0, 0, 0);
      }
    }
  }

  lsum += __shfl_xor(lsum, 16);
  lsum += __shfl_xor(lsum, 32);
  if (lane < 16) sRow[w*16 + lane] = lsum;
  float rs[4];
  for (int r = 0; r < 4; ++r) rs[r] = sRow[w*16 + quad*4 + r];
  for (int nt = 0; nt < 4; ++nt)
    for (int r = 0; r < 4; ++r) {
      float v = o[nt][r] / rs[r];
      size_t m = (size_t)(b*S_ + q0 + wq + quad*4 + r);
      AO[m * 512 + h*64 + nt*16 + col] = f2bf(v);
    }
}

// ===========================================================================
extern "C" void kernel_launch(void* const* d_in, const int* in_sizes, int n_in,
                              void* d_out, int out_size, void* d_ws, size_t ws_size,
                              hipStream_t stream)
{
  const float* x    = (const float*)d_in[0];
  const float* f0   = (const float*)d_in[1];
  const float* sp   = (const float*)d_in[2];
  const float* ap   = (const float*)d_in[3];
  const float* spk  = (const float*)d_in[4];
  const float* Wf0  = (const float*)d_in[5];  const float* bf0  = (const float*)d_in[6];
  const float* Wsp  = (const float*)d_in[7];  const float* bsp  = (const float*)d_in[8];
  const float* Wap  = (const float*)d_in[9];  const float* bap  = (const float*)d_in[10];
  const float* Wspk = (const float*)d_in[11]; const float* bspk = (const float*)d_in[12];
  const float* Wq   = (const float*)d_in[13]; const float* bq   = (const float*)d_in[14];
  const float* Wk   = (const float*)d_in[15]; const float* bk   = (const float*)d_in[16];
  const float* Wv   = (const float*)d_in[17]; const float* bv   = (const float*)d_in[18];
  const float* Wo   = (const float*)d_in[19]; const float* bo   = (const float*)d_in[20];
  const float* ln1g = (const float*)d_in[21]; const float* ln1b = (const float*)d_in[22];
  const float* ln2g = (const float*)d_in[23]; const float* ln2b = (const float*)d_in[24];
  const float* W1   = (const float*)d_in[25]; const float* b1   = (const float*)d_in[26];
  const float* W2   = (const float*)d_in[27]; const float* b2   = (const float*)d_in[28];
  const float* tab  = (const float*)d_in[29];
  const float* gfin = (const float*)d_in[30]; const float* bfin = (const float*)d_in[31];

  char* p = (char*)d_ws;
  auto alloc = [&](size_t bytes) { char* r = p; p += (bytes + 255) & ~(size_t)255; return r; };
  short* WqkvT = (short*)alloc((size_t)L_ * 1536 * 512 * 2);
  short* WoT   = (short*)alloc((size_t)L_ * 512 * 512 * 2);
  short* W1T   = (short*)alloc((size_t)L_ * 2048 * 512 * 2);
  short* W2T   = (short*)alloc((size_t)L_ * 512 * 2048 * 2);
  float* bqkv  = (float*)alloc((size_t)L_ * 1536 * 4);
  float* X     = (float*)alloc((size_t)M_ * D_ * 4);
  short* Hb    = (short*)alloc((size_t)M_ * D_ * 2);
  short* AO    = (short*)alloc((size_t)M_ * D_ * 2);
  short* QKVb  = (short*)alloc((size_t)M_ * 1536 * 2);
  short* VtG   = (short*)alloc((size_t)B_ * H_ * HD_ * S_ * 2);
  short* H1b   = QKVb;  // alias: FFN hidden (M,F) reuses QKVb+VtG region (exactly 16 MB)
  float* sproj = (float*)alloc((size_t)B_ * D_ * 4);
  float* tabT  = (float*)alloc((size_t)L_ * H_ * NREL_ * 4);

  dim3 b256(256);
  dim3 tb(32, 8);
  packb_kernel<<<dim3((L_*1536 + 255)/256), b256, 0, stream>>>(bq, bk, bv, bqkv);
  tabt_kernel<<<dim3((L_*H_*NREL_ + 255)/256), b256, 0, stream>>>(tab, tabT);
  transpose_kernel<<<dim3(16, 16, L_), tb, 0, stream>>>(Wq, WqkvT, 512, 512, 512*512, 1536*512, 0);
  transpose_kernel<<<dim3(16, 16, L_), tb, 0, stream>>>(Wk, WqkvT, 512, 512, 512*512, 1536*512, 512);
  transpose_kernel<<<dim3(16, 16, L_), tb, 0, stream>>>(Wv, WqkvT, 512, 512, 512*512, 1536*512, 1024);
  transpose_kernel<<<dim3(16, 16, L_), tb, 0, stream>>>(Wo, WoT, 512, 512, 512*512, 512*512, 0);
  transpose_kernel<<<dim3(64, 16, L_), tb, 0, stream>>>(W1, W1T, 512, 2048, 512*2048, 2048*512, 0);
  transpose_kernel<<<dim3(16, 64, L_), tb, 0, stream>>>(W2, W2T, 2048, 512, 2048*512, 512*2048, 0);
  spk_kernel<<<dim3(B_, 8), b256, 0, stream>>>(spk, Wspk, bspk, sproj);
  prologue_kernel<<<dim3(M_), b256, 0, stream>>>(x, f0, sp, ap, Wf0, bf0, Wsp, bsp, Wap, bap, sproj, X);

  for (int l = 0; l < L_; ++l) {
    ln_kernel<<<dim3(M_), b256, 0, stream>>>(X, ln1g + l*D_, ln1b + l*D_, Hb, nullptr, 0);
    gemm_qkv_kernel<<<dim3(32, 24, 1), b256, 0, stream>>>(
        Hb, WqkvT + (size_t)l*1536*512, bqkv + l*1536, nullptr, QKVb);
    vtrans_kernel<<<dim3(S_/64, B_*H_), b256, 0, stream>>>(QKVb, VtG);
    flash_kernel<<<dim3(B_*H_, S_/128), dim3(512), 0, stream>>>(QKVb, VtG, tabT + (size_t)l*H_*NREL_, AO);
    gemm_o_kernel<<<dim3(32, 8, 2), b256, 0, stream>>>(
        AO, WoT + (size_t)l*512*512, bo + l*D_, X, nullptr);
    ln_kernel<<<dim3(M_), b256, 0, stream>>>(X, ln2g + l*D_, ln2b + l*D_, Hb, nullptr, 0);
    gemm_ffn1_kernel<<<dim3(32, 32, 1), b256, 0, stream>>>(
        Hb, W1T + (size_t)l*2048*512, b1 + l*F_, nullptr, H1b);
    gemm_ffn2_kernel<<<dim3(32, 8, 4), b256, 0, stream>>>(
        H1b, W2T + (size_t)l*512*2048, b2 + l*D_, X, nullptr);
  }
  ln_kernel<<<dim3(M_), b256, 0, stream>>>(X, gfin, bfin, nullptr, (float*)d_out, 1);
}